// Round 1
// baseline (1061.513 us; speedup 1.0000x reference)
//
#include <hip/hip_runtime.h>
#include <math.h>
#include <cstddef>

// Problem constants
#define BB   16
#define HH   256
#define WW   256
#define CC   64      // channels (= attention token count)
#define NTOK 16      // pooled tokens per (b,c)
#define NDIM 16      // DIM

// ws layout (floats):
//   part : [B][16 tok][16 rc][64 c]  = 262144 floats (1 MiB)
//   attnT: [B][64 c][64 t]           =  65536 floats (256 KiB)
#define PART_FLOATS (BB * NTOK * 16 * CC)

typedef float f32x2 __attribute__((ext_vector_type(2)));
typedef float f32x4 __attribute__((ext_vector_type(4)));

// ---------------------------------------------------------------------------
// Stage 1: partial pooling sums.
// grid = B*16tok*16rc = 4096 blocks, 256 threads.
// Block handles a 4-row x 64-col strip of one 64x64 patch, all 64 channels.
// Wave reads 1 KiB fully-coalesced per float4 instruction.
// NOTE: normal (caching) loads on purpose — this pass warms the 256 MiB L3
// with x (exactly 256 MiB), which out_kernel re-reads.
// ---------------------------------------------------------------------------
__global__ __launch_bounds__(256) void pool_partial(const float* __restrict__ x,
                                                    float* __restrict__ part) {
    const int blk = blockIdx.x;       // b*256 + n*16 + rc
    const int rc  = blk & 15;
    const int n   = (blk >> 4) & 15;
    const int b   = blk >> 8;
    const int ph  = n >> 2, pw = n & 3;
    const int t   = threadIdx.x;
    const int c4  = (t & 15) << 2;
    const int sub = t >> 4;           // 0..15

    const int h0 = ph * 64 + rc * 4;
    const int w0 = pw * 64;
    const float* xb = x + (((size_t)b * HH + h0) * WW + w0) * CC;

    float4 s = make_float4(0.f, 0.f, 0.f, 0.f);
#pragma unroll
    for (int k = 0; k < 16; ++k) {
        const int pos = sub + (k << 4);       // 0..255
        const int row = pos >> 6;
        const int col = pos & 63;
        const float4 v = *(const float4*)(xb + ((size_t)row * WW + col) * CC + c4);
        s.x += v.x; s.y += v.y; s.z += v.z; s.w += v.w;
    }

    __shared__ float lds[16 * 64];
    lds[sub * 64 + c4 + 0] = s.x;
    lds[sub * 64 + c4 + 1] = s.y;
    lds[sub * 64 + c4 + 2] = s.z;
    lds[sub * 64 + c4 + 3] = s.w;
    __syncthreads();

    if (t < 64) {
        float acc = 0.f;
#pragma unroll
        for (int ss = 0; ss < 16; ++ss) acc += lds[ss * 64 + t];
        part[(((size_t)b * NTOK + n) * 16 + rc) * CC + t] = acc;
    }
}

// ---------------------------------------------------------------------------
// Stage 2: tokens -> qk -> dots -> softmax -> attnT. grid = 16 (one per batch).
// attnT[b][c][t] = attn[b][t][c]  (t contiguous, for stage-3 uniform loads)
// ---------------------------------------------------------------------------
__global__ __launch_bounds__(256) void attn_kernel(const float* __restrict__ part,
                                                   const float* __restrict__ w_qkv, // [32][16]
                                                   float* __restrict__ attnT) {
    const int b = blockIdx.x;
    const int t = threadIdx.x;

    __shared__ float tok[CC * NDIM];   // [c][n]
    __shared__ float ql [CC * NDIM];   // [c][n]
    __shared__ float kl [CC * NDIM];   // [c][n]
    __shared__ float dl [CC * CC];     // [i][j]
    __shared__ float rs [CC];          // 1/rowsum

    const float* pb = part + (size_t)b * NTOK * 16 * CC;

    // tokens[c][n] = mean over patch = (sum of 16 rc-partials)/4096
    for (int idx = t; idx < CC * NDIM; idx += 256) {
        const int c = idx >> 4, n = idx & 15;
        float a = 0.f;
#pragma unroll
        for (int rc = 0; rc < 16; ++rc) a += pb[((size_t)n * 16 + rc) * CC + c];
        tok[c * NDIM + n] = a * (1.0f / 4096.0f);
    }
    __syncthreads();

    // qk[c][d] = sum_n tok[c][n] * w[d][n];  split into q (d<16) and k
    for (int idx = t; idx < CC * 32; idx += 256) {
        const int c = idx >> 5, d = idx & 31;
        float a = 0.f;
#pragma unroll
        for (int n = 0; n < NDIM; ++n) a += tok[c * NDIM + n] * w_qkv[d * NDIM + n];
        if (d < 16) ql[c * NDIM + d] = a;
        else        kl[c * NDIM + (d - 16)] = a;
    }
    __syncthreads();

    // dots[i][j] = 0.25 * sum_n q[i][n]*k[j][n]
    for (int idx = t; idx < CC * CC; idx += 256) {
        const int i = idx >> 6, j = idx & 63;
        float a = 0.f;
#pragma unroll
        for (int n = 0; n < NDIM; ++n) a += ql[i * NDIM + n] * kl[j * NDIM + n];
        dl[idx] = a * 0.25f;
    }
    __syncthreads();

    // row softmax (64 rows, one thread each — tiny)
    if (t < CC) {
        float m = -1e30f;
        for (int j = 0; j < CC; ++j) m = fmaxf(m, dl[t * CC + j]);
        float ssum = 0.f;
        for (int j = 0; j < CC; ++j) {
            const float e = expf(dl[t * CC + j] - m);
            dl[t * CC + j] = e;
            ssum += e;
        }
        rs[t] = 1.0f / ssum;
    }
    __syncthreads();

    // attnT[b][c][t2] = dl[t2][c] * rs[t2]
    for (int idx = t; idx < CC * CC; idx += 256) {
        const int tt = idx & 63;        // idx = c*64 + t2
        attnT[(size_t)b * (CC * CC) + idx] = dl[tt * CC + (idx >> 6)] * rs[tt];
    }
}

// ---------------------------------------------------------------------------
// Stage 3: out[p][t] = gelu( sum_c x[p][c] * attnT[c][t] )
// Block = 256 threads = 4 waves, handles 64 pixels. Thread (lane=pixel,
// th=waveId) computes 16 tokens.
// v2 changes:
//  - f32x2 packed accumulators + __builtin_elementwise_fma -> v_pk_fma_f32
//    (gfx950 full-rate packed fp32): halves FMA issue cycles.
//  - __builtin_nontemporal_store for the 268 MB output: stops write-allocate
//    from evicting x (exactly 256 MiB, L3-resident after pool_partial).
//    Prior counters: FETCH_SIZE=133 MB on a pass that should be ~all L3 hits.
// th is wave-uniform (readfirstlane) so attn chunk loads are scalar s_loads.
// x is staged via LDS: coalesced float4 global loads; stride-65 padding makes
// the per-c LDS reads 2-lanes/bank (free, m136).
// ---------------------------------------------------------------------------
__device__ __forceinline__ float gelu_exact(float v) {
    return 0.5f * v * (1.0f + erff(v * 0.70710678118654752f));
}

#define XPAD 65   // LDS row stride in floats

__global__ __launch_bounds__(256) void out_kernel(const float* __restrict__ x,
                                                  const float* __restrict__ attnT,
                                                  float* __restrict__ out) {
    const int tid  = threadIdx.x;
    const int lane = tid & 63;                               // pixel within block
    const int th   = __builtin_amdgcn_readfirstlane(tid >> 6); // token quarter, wave-uniform
    const int blk  = blockIdx.x;                             // 16384 blocks
    const int b    = blk >> 10;                              // 1024 blocks per batch
    const size_t pixbase = (size_t)blk * 64;

    __shared__ float xt[64 * XPAD];

    // Cooperative stage of 64 pixel rows (16 KiB): 1024 float4 loads, coalesced.
    const float4* xsrc = (const float4*)(x + pixbase * CC);
#pragma unroll
    for (int it = 0; it < 4; ++it) {
        const int i  = tid + it * 256;       // float4 index 0..1023
        const float4 v = xsrc[i];
        const int px = i >> 4;               // (i*4)/64
        const int c0 = (i << 2) & 63;
        float* d = &xt[px * XPAD + c0];
        d[0] = v.x; d[1] = v.y; d[2] = v.z; d[3] = v.w;
    }
    __syncthreads();

    // attn chunk base for this wave: 16 consecutive t's, uniform address.
    const float* __restrict__ at = attnT + (size_t)b * (CC * CC) + th * 16;
    const float* __restrict__ xr = &xt[lane * XPAD];

    f32x2 a0 = {0.f, 0.f};
    f32x2 a1 = a0, a2 = a0, a3 = a0, a4 = a0, a5 = a0, a6 = a0, a7 = a0;

#pragma unroll 4
    for (int c = 0; c < CC; ++c) {
        const float xc = xr[c];
        const f32x2 xc2 = {xc, xc};
        const f32x4 w0 = *(const f32x4*)(at + c * CC + 0);
        const f32x4 w1 = *(const f32x4*)(at + c * CC + 4);
        const f32x4 w2 = *(const f32x4*)(at + c * CC + 8);
        const f32x4 w3 = *(const f32x4*)(at + c * CC + 12);
        a0 = __builtin_elementwise_fma(xc2, w0.lo, a0);
        a1 = __builtin_elementwise_fma(xc2, w0.hi, a1);
        a2 = __builtin_elementwise_fma(xc2, w1.lo, a2);
        a3 = __builtin_elementwise_fma(xc2, w1.hi, a3);
        a4 = __builtin_elementwise_fma(xc2, w2.lo, a4);
        a5 = __builtin_elementwise_fma(xc2, w2.hi, a5);
        a6 = __builtin_elementwise_fma(xc2, w3.lo, a6);
        a7 = __builtin_elementwise_fma(xc2, w3.hi, a7);
    }

    // Epilogue: exact GELU + 4x16B non-temporal stores (don't evict x from L3).
    f32x4* op = (f32x4*)(out + (pixbase + lane) * CC + th * 16);
    f32x4 g;
    g.x = gelu_exact(a0.x); g.y = gelu_exact(a0.y); g.z = gelu_exact(a1.x); g.w = gelu_exact(a1.y);
    __builtin_nontemporal_store(g, op + 0);
    g.x = gelu_exact(a2.x); g.y = gelu_exact(a2.y); g.z = gelu_exact(a3.x); g.w = gelu_exact(a3.y);
    __builtin_nontemporal_store(g, op + 1);
    g.x = gelu_exact(a4.x); g.y = gelu_exact(a4.y); g.z = gelu_exact(a5.x); g.w = gelu_exact(a5.y);
    __builtin_nontemporal_store(g, op + 2);
    g.x = gelu_exact(a6.x); g.y = gelu_exact(a6.y); g.z = gelu_exact(a7.x); g.w = gelu_exact(a7.y);
    __builtin_nontemporal_store(g, op + 3);
}

// ---------------------------------------------------------------------------
extern "C" void kernel_launch(void* const* d_in, const int* in_sizes, int n_in,
                              void* d_out, int out_size, void* d_ws, size_t ws_size,
                              hipStream_t stream) {
    const float* x     = (const float*)d_in[0];   // (16,256,256,64) fp32
    const float* w_qkv = (const float*)d_in[1];   // (32,16) fp32
    float* out   = (float*)d_out;                 // (16,256,256,64) fp32
    float* part  = (float*)d_ws;                  // 1 MiB
    float* attnT = part + PART_FLOATS;            // 256 KiB

    pool_partial<<<BB * NTOK * 16, 256, 0, stream>>>(x, part);
    attn_kernel<<<BB, 256, 0, stream>>>(part, w_qkv, attnT);
    out_kernel<<<BB * 256 * 4, 256, 0, stream>>>(x, attnT, out);
}

// Round 2
// 553.570 us; speedup vs baseline: 1.9176x; 1.9176x over previous
//
#include <hip/hip_runtime.h>
#include <math.h>
#include <cstddef>

// Problem constants
#define BB   16
#define HH   256
#define WW   256
#define CC   64      // channels (= attention token count)
#define NTOK 16      // pooled tokens per (b,c)
#define NDIM 16      // DIM

// ws layout (floats):
//   part : [B][16 tok][16 rc][64 c]  = 262144 floats (1 MiB)
//   attnT: [B][64 c][64 t]           =  65536 floats (256 KiB)
#define PART_FLOATS (BB * NTOK * 16 * CC)

typedef float f32x2 __attribute__((ext_vector_type(2)));
typedef float f32x4 __attribute__((ext_vector_type(4)));

// ---------------------------------------------------------------------------
// Stage 1: partial pooling sums.
// grid = B*16tok*16rc = 4096 blocks, 256 threads.
// Block handles a 4-row x 64-col strip of one 64x64 patch, all 64 channels.
// Wave reads 1 KiB fully-coalesced per float4 instruction.
// ---------------------------------------------------------------------------
__global__ __launch_bounds__(256) void pool_partial(const float* __restrict__ x,
                                                    float* __restrict__ part) {
    const int blk = blockIdx.x;       // b*256 + n*16 + rc
    const int rc  = blk & 15;
    const int n   = (blk >> 4) & 15;
    const int b   = blk >> 8;
    const int ph  = n >> 2, pw = n & 3;
    const int t   = threadIdx.x;
    const int c4  = (t & 15) << 2;
    const int sub = t >> 4;           // 0..15

    const int h0 = ph * 64 + rc * 4;
    const int w0 = pw * 64;
    const float* xb = x + (((size_t)b * HH + h0) * WW + w0) * CC;

    float4 s = make_float4(0.f, 0.f, 0.f, 0.f);
#pragma unroll
    for (int k = 0; k < 16; ++k) {
        const int pos = sub + (k << 4);       // 0..255
        const int row = pos >> 6;
        const int col = pos & 63;
        const float4 v = *(const float4*)(xb + ((size_t)row * WW + col) * CC + c4);
        s.x += v.x; s.y += v.y; s.z += v.z; s.w += v.w;
    }

    __shared__ float lds[16 * 64];
    lds[sub * 64 + c4 + 0] = s.x;
    lds[sub * 64 + c4 + 1] = s.y;
    lds[sub * 64 + c4 + 2] = s.z;
    lds[sub * 64 + c4 + 3] = s.w;
    __syncthreads();

    if (t < 64) {
        float acc = 0.f;
#pragma unroll
        for (int ss = 0; ss < 16; ++ss) acc += lds[ss * 64 + t];
        part[(((size_t)b * NTOK + n) * 16 + rc) * CC + t] = acc;
    }
}

// ---------------------------------------------------------------------------
// Stage 2: tokens -> qk -> dots -> softmax -> attnT. grid = 16 (one per batch).
// attnT[b][c][t] = attn[b][t][c]  (t contiguous, for stage-3 uniform loads)
// ---------------------------------------------------------------------------
__global__ __launch_bounds__(256) void attn_kernel(const float* __restrict__ part,
                                                   const float* __restrict__ w_qkv, // [32][16]
                                                   float* __restrict__ attnT) {
    const int b = blockIdx.x;
    const int t = threadIdx.x;

    __shared__ float tok[CC * NDIM];   // [c][n]
    __shared__ float ql [CC * NDIM];   // [c][n]
    __shared__ float kl [CC * NDIM];   // [c][n]
    __shared__ float dl [CC * CC];     // [i][j]
    __shared__ float rs [CC];          // 1/rowsum

    const float* pb = part + (size_t)b * NTOK * 16 * CC;

    // tokens[c][n] = mean over patch = (sum of 16 rc-partials)/4096
    for (int idx = t; idx < CC * NDIM; idx += 256) {
        const int c = idx >> 4, n = idx & 15;
        float a = 0.f;
#pragma unroll
        for (int rc = 0; rc < 16; ++rc) a += pb[((size_t)n * 16 + rc) * CC + c];
        tok[c * NDIM + n] = a * (1.0f / 4096.0f);
    }
    __syncthreads();

    // qk[c][d] = sum_n tok[c][n] * w[d][n];  split into q (d<16) and k
    for (int idx = t; idx < CC * 32; idx += 256) {
        const int c = idx >> 5, d = idx & 31;
        float a = 0.f;
#pragma unroll
        for (int n = 0; n < NDIM; ++n) a += tok[c * NDIM + n] * w_qkv[d * NDIM + n];
        if (d < 16) ql[c * NDIM + d] = a;
        else        kl[c * NDIM + (d - 16)] = a;
    }
    __syncthreads();

    // dots[i][j] = 0.25 * sum_n q[i][n]*k[j][n]
    for (int idx = t; idx < CC * CC; idx += 256) {
        const int i = idx >> 6, j = idx & 63;
        float a = 0.f;
#pragma unroll
        for (int n = 0; n < NDIM; ++n) a += ql[i * NDIM + n] * kl[j * NDIM + n];
        dl[idx] = a * 0.25f;
    }
    __syncthreads();

    // row softmax (64 rows, one thread each — tiny)
    if (t < CC) {
        float m = -1e30f;
        for (int j = 0; j < CC; ++j) m = fmaxf(m, dl[t * CC + j]);
        float ssum = 0.f;
        for (int j = 0; j < CC; ++j) {
            const float e = expf(dl[t * CC + j] - m);
            dl[t * CC + j] = e;
            ssum += e;
        }
        rs[t] = 1.0f / ssum;
    }
    __syncthreads();

    // attnT[b][c][t2] = dl[t2][c] * rs[t2]
    for (int idx = t; idx < CC * CC; idx += 256) {
        const int tt = idx & 63;        // idx = c*64 + t2
        attnT[(size_t)b * (CC * CC) + idx] = dl[tt * CC + (idx >> 6)] * rs[tt];
    }
}

// ---------------------------------------------------------------------------
// Stage 3: out[p][t] = gelu( sum_c x[p][c] * attnT[c][t] )
// Block = 256 threads = 4 waves, handles 64 pixels. Thread (lane=pixel,
// th=waveId) computes 16 tokens.
// v3 changes vs v1 (the 166 us version):
//  - NORMAL caching stores (v2's nontemporal stores caused exact 4x HBM write
//    amplification: 16B/lane at 256B stride never merges without L2
//    write-back. WRITE_SIZE 1.08GB -> must return to ~270MB).
//  - True packed fp32 FMA via inline-asm v_pk_fma_f32. The attn row is
//    wave-uniform and scalarized by the compiler (SGPR_Count=96): use an
//    "s" 64-bit-pair constraint for the weight operand (VOP3P permits one
//    SGPR-pair source), keeping xc2/acc in VGPRs. Halves FMA issue count
//    (1024 -> 512 per wave).
// th is wave-uniform (readfirstlane) so attn chunk loads are scalar s_loads.
// x is staged via LDS: coalesced float4 global loads; stride-65 padding makes
// the per-c LDS reads 2-lanes/bank (free, m136).
// ---------------------------------------------------------------------------
__device__ __forceinline__ float gelu_exact(float v) {
    return 0.5f * v * (1.0f + erff(v * 0.70710678118654752f));
}

#define XPAD 65   // LDS row stride in floats

__global__ __launch_bounds__(256) void out_kernel(const float* __restrict__ x,
                                                  const float* __restrict__ attnT,
                                                  float* __restrict__ out) {
    const int tid  = threadIdx.x;
    const int lane = tid & 63;                               // pixel within block
    const int th   = __builtin_amdgcn_readfirstlane(tid >> 6); // token quarter, wave-uniform
    const int blk  = blockIdx.x;                             // 16384 blocks
    const int b    = blk >> 10;                              // 1024 blocks per batch
    const size_t pixbase = (size_t)blk * 64;

    __shared__ float xt[64 * XPAD];

    // Cooperative stage of 64 pixel rows (16 KiB): 1024 float4 loads, coalesced.
    const float4* xsrc = (const float4*)(x + pixbase * CC);
#pragma unroll
    for (int it = 0; it < 4; ++it) {
        const int i  = tid + it * 256;       // float4 index 0..1023
        const float4 v = xsrc[i];
        const int px = i >> 4;               // (i*4)/64
        const int c0 = (i << 2) & 63;
        float* d = &xt[px * XPAD + c0];
        d[0] = v.x; d[1] = v.y; d[2] = v.z; d[3] = v.w;
    }
    __syncthreads();

    // attn chunk base for this wave: 16 consecutive t's, uniform address.
    const float* __restrict__ at = attnT + (size_t)b * (CC * CC) + th * 16;
    const float* __restrict__ xr = &xt[lane * XPAD];

    f32x2 a0 = {0.f, 0.f};
    f32x2 a1 = a0, a2 = a0, a3 = a0, a4 = a0, a5 = a0, a6 = a0, a7 = a0;

#pragma unroll 4
    for (int c = 0; c < CC; ++c) {
        const float xc = xr[c];
        f32x2 xc2; xc2.x = xc; xc2.y = xc;
        const f32x2* w = (const f32x2*)(at + c * CC);
        // acc = w * xc2 + acc  (packed fp32, weight pair from SGPRs)
        asm("v_pk_fma_f32 %0, %1, %2, %0" : "+v"(a0) : "s"(w[0]), "v"(xc2));
        asm("v_pk_fma_f32 %0, %1, %2, %0" : "+v"(a1) : "s"(w[1]), "v"(xc2));
        asm("v_pk_fma_f32 %0, %1, %2, %0" : "+v"(a2) : "s"(w[2]), "v"(xc2));
        asm("v_pk_fma_f32 %0, %1, %2, %0" : "+v"(a3) : "s"(w[3]), "v"(xc2));
        asm("v_pk_fma_f32 %0, %1, %2, %0" : "+v"(a4) : "s"(w[4]), "v"(xc2));
        asm("v_pk_fma_f32 %0, %1, %2, %0" : "+v"(a5) : "s"(w[5]), "v"(xc2));
        asm("v_pk_fma_f32 %0, %1, %2, %0" : "+v"(a6) : "s"(w[6]), "v"(xc2));
        asm("v_pk_fma_f32 %0, %1, %2, %0" : "+v"(a7) : "s"(w[7]), "v"(xc2));
    }

    // Epilogue: exact GELU + 4x16B normal stores (L2 write-back merges the
    // 256B-strided lane pattern into full lines across the block's 4 waves).
    float* op = out + (pixbase + lane) * CC + th * 16;
    float4 g;
    g.x = gelu_exact(a0.x); g.y = gelu_exact(a0.y); g.z = gelu_exact(a1.x); g.w = gelu_exact(a1.y);
    ((float4*)op)[0] = g;
    g.x = gelu_exact(a2.x); g.y = gelu_exact(a2.y); g.z = gelu_exact(a3.x); g.w = gelu_exact(a3.y);
    ((float4*)op)[1] = g;
    g.x = gelu_exact(a4.x); g.y = gelu_exact(a4.y); g.z = gelu_exact(a5.x); g.w = gelu_exact(a5.y);
    ((float4*)op)[2] = g;
    g.x = gelu_exact(a6.x); g.y = gelu_exact(a6.y); g.z = gelu_exact(a7.x); g.w = gelu_exact(a7.y);
    ((float4*)op)[3] = g;
}

// ---------------------------------------------------------------------------
extern "C" void kernel_launch(void* const* d_in, const int* in_sizes, int n_in,
                              void* d_out, int out_size, void* d_ws, size_t ws_size,
                              hipStream_t stream) {
    const float* x     = (const float*)d_in[0];   // (16,256,256,64) fp32
    const float* w_qkv = (const float*)d_in[1];   // (32,16) fp32
    float* out   = (float*)d_out;                 // (16,256,256,64) fp32
    float* part  = (float*)d_ws;                  // 1 MiB
    float* attnT = part + PART_FLOATS;            // 256 KiB

    pool_partial<<<BB * NTOK * 16, 256, 0, stream>>>(x, part);
    attn_kernel<<<BB, 256, 0, stream>>>(part, w_qkv, attnT);
    out_kernel<<<BB * 256 * 4, 256, 0, stream>>>(x, attnT, out);
}

// Round 4
// 507.283 us; speedup vs baseline: 2.0925x; 1.0912x over previous
//
#include <hip/hip_runtime.h>
#include <math.h>
#include <cstddef>

// Problem constants
#define BB   16
#define HH   256
#define WW   256
#define CC   64      // channels (= attention token count)
#define NTOK 16      // pooled tokens per (b,c)
#define NDIM 16      // DIM

// ws layout:
//   part : [B][16 tok][16 rc][64 c] fp32   = 262144 floats (1 MiB)
//   frag : [B][16 slot][64 lane][8 j] bf16 = 131072 ushorts (256 KiB)
//     per-batch size: 16*64*8 = 8192 ushorts = 1024 fragments of 16 B.
//     slot = ((tcol*2 + kstep)*2 + split); split 0=hi, 1=lo
//     element: W[t = tcol*16 + (lane&15)][c = kstep*32 + (lane>>4)*8 + j]
//     i.e. the exact mfma_f32_16x16x32_bf16 B-fragment layout.
#define PART_FLOATS (BB * NTOK * 16 * CC)
#define FRAG_USHORT_PER_B (16 * 64 * 8)   // 8192

typedef short s16x8 __attribute__((ext_vector_type(8)));   // 8 bf16 (4 VGPRs)
typedef float f32x4 __attribute__((ext_vector_type(4)));

// bf16 helpers (RNE)
__device__ __forceinline__ unsigned short f2bf_rne(float f) {
    unsigned int u = __float_as_uint(f);
    return (unsigned short)((u + 0x7fffu + ((u >> 16) & 1u)) >> 16);
}
__device__ __forceinline__ float bf2f(unsigned short h) {
    return __uint_as_float(((unsigned int)h) << 16);
}

// ---------------------------------------------------------------------------
// Stage 1: partial pooling sums. (unchanged — ~50 us, near coalesced floor)
// ---------------------------------------------------------------------------
__global__ __launch_bounds__(256) void pool_partial(const float* __restrict__ x,
                                                    float* __restrict__ part) {
    const int blk = blockIdx.x;       // b*256 + n*16 + rc
    const int rc  = blk & 15;
    const int n   = (blk >> 4) & 15;
    const int b   = blk >> 8;
    const int ph  = n >> 2, pw = n & 3;
    const int t   = threadIdx.x;
    const int c4  = (t & 15) << 2;
    const int sub = t >> 4;           // 0..15

    const int h0 = ph * 64 + rc * 4;
    const int w0 = pw * 64;
    const float* xb = x + (((size_t)b * HH + h0) * WW + w0) * CC;

    float4 s = make_float4(0.f, 0.f, 0.f, 0.f);
#pragma unroll
    for (int k = 0; k < 16; ++k) {
        const int pos = sub + (k << 4);       // 0..255
        const int row = pos >> 6;
        const int col = pos & 63;
        const float4 v = *(const float4*)(xb + ((size_t)row * WW + col) * CC + c4);
        s.x += v.x; s.y += v.y; s.z += v.z; s.w += v.w;
    }

    __shared__ float lds[16 * 64];
    lds[sub * 64 + c4 + 0] = s.x;
    lds[sub * 64 + c4 + 1] = s.y;
    lds[sub * 64 + c4 + 2] = s.z;
    lds[sub * 64 + c4 + 3] = s.w;
    __syncthreads();

    if (t < 64) {
        float acc = 0.f;
#pragma unroll
        for (int ss = 0; ss < 16; ++ss) acc += lds[ss * 64 + t];
        part[(((size_t)b * NTOK + n) * 16 + rc) * CC + t] = acc;
    }
}

// ---------------------------------------------------------------------------
// Stage 2: tokens -> qk -> dots -> softmax -> bf16-split B-fragments.
// grid = 16 (one per batch).
// ---------------------------------------------------------------------------
__global__ __launch_bounds__(256) void attn_kernel(const float* __restrict__ part,
                                                   const float* __restrict__ w_qkv, // [32][16]
                                                   unsigned short* __restrict__ fragw) {
    const int b = blockIdx.x;
    const int t = threadIdx.x;

    __shared__ float tok[CC * NDIM];   // [c][n]
    __shared__ float ql [CC * NDIM];   // [c][n]
    __shared__ float kl [CC * NDIM];   // [c][n]
    __shared__ float dl [CC * CC];     // [i][j]
    __shared__ float rs [CC];          // 1/rowsum

    const float* pb = part + (size_t)b * NTOK * 16 * CC;

    // tokens[c][n] = mean over patch = (sum of 16 rc-partials)/4096
    for (int idx = t; idx < CC * NDIM; idx += 256) {
        const int c = idx >> 4, n = idx & 15;
        float a = 0.f;
#pragma unroll
        for (int rc = 0; rc < 16; ++rc) a += pb[((size_t)n * 16 + rc) * CC + c];
        tok[c * NDIM + n] = a * (1.0f / 4096.0f);
    }
    __syncthreads();

    // qk[c][d] = sum_n tok[c][n] * w[d][n];  split into q (d<16) and k
    for (int idx = t; idx < CC * 32; idx += 256) {
        const int c = idx >> 5, d = idx & 31;
        float a = 0.f;
#pragma unroll
        for (int n = 0; n < NDIM; ++n) a += tok[c * NDIM + n] * w_qkv[d * NDIM + n];
        if (d < 16) ql[c * NDIM + d] = a;
        else        kl[c * NDIM + (d - 16)] = a;
    }
    __syncthreads();

    // dots[i][j] = 0.25 * sum_n q[i][n]*k[j][n]
    for (int idx = t; idx < CC * CC; idx += 256) {
        const int i = idx >> 6, j = idx & 63;
        float a = 0.f;
#pragma unroll
        for (int n = 0; n < NDIM; ++n) a += ql[i * NDIM + n] * kl[j * NDIM + n];
        dl[idx] = a * 0.25f;
    }
    __syncthreads();

    // row softmax (64 rows, one thread each — tiny)
    if (t < CC) {
        float m = -1e30f;
        for (int j = 0; j < CC; ++j) m = fmaxf(m, dl[t * CC + j]);
        float ssum = 0.f;
        for (int j = 0; j < CC; ++j) {
            const float e = expf(dl[t * CC + j] - m);
            dl[t * CC + j] = e;
            ssum += e;
        }
        rs[t] = 1.0f / ssum;
    }
    __syncthreads();

    // Emit attn[t][c] = dl[t][c]*rs[t] as bf16 hi/lo MFMA B-fragments.
    // 512 work items: (t, octet-of-c). Each writes two 16 B fragments.
    for (int idx = t; idx < 512; idx += 256) {
        const int tt   = idx >> 3;          // 0..63
        const int oct  = idx & 7;           // c octet
        const int ks   = oct >> 2;          // kstep = c>>5
        const int g    = oct & 3;           // lane>>4 group
        const int slot = ((tt >> 4) * 2 + ks) * 2;   // +0 hi, +1 lo
        const int lanei = (tt & 15) + g * 16;
        const float rr = rs[tt];
        s16x8 hi, lo;
#pragma unroll
        for (int j = 0; j < 8; ++j) {
            const float w = dl[tt * CC + oct * 8 + j] * rr;
            const unsigned short h = f2bf_rne(w);
            hi[j] = (short)h;
            lo[j] = (short)f2bf_rne(w - bf2f(h));
        }
        s16x8* dst = (s16x8*)fragw + ((size_t)b * 16 + slot) * 64;
        dst[lanei]      = hi;   // slot   (split=0)
        dst[64 + lanei] = lo;   // slot+1 (split=1)
    }
}

// ---------------------------------------------------------------------------
// Stage 3 (v5): MFMA GEMM. out[p][t] = gelu( sum_c x[p][c] * attn[t][c] )
// Per batch: [65536 x 64c] @ [64c x 64t] with 2-term bf16 split:
//   out ~= xh*wh + xl*wh + xh*wl     (xl*wl ~ 2^-18 rel, dropped)
// v5 fixes vs v4 (failed, absmax 0.43):
//   - batch stride of frag read was b*16384 ushorts; correct is b*8192
//     (16 slots * 64 lanes * 8). b>=1 read the wrong batch's attention.
//   - LDS staging copied 2048 fragments into a 1024-fragment buffer
//     (16 KiB OOB LDS write). Correct: 4 iters x 256 threads = 1024 frags.
// Block = 256 threads = 4 waves; wave owns 64 pixels x 64 t. x loads are
// direct global->VGPR, fully coalesced; B-fragments staged once to LDS
// (16 KiB), 16B/lane conflict-free reads.
// A-frag: lane l -> row l&15, k (l>>4)*8+j (m92-m97 refchecked);
// C/D: col=lane&15, row=(lane>>4)*4+reg (m89-verified).
// ---------------------------------------------------------------------------
__device__ __forceinline__ float gelu_exact(float v) {
    return 0.5f * v * (1.0f + erff(v * 0.70710678118654752f));
}

__device__ __forceinline__ void split8(const float4 v0, const float4 v1,
                                       s16x8& hi, s16x8& lo) {
    const float f[8] = {v0.x, v0.y, v0.z, v0.w, v1.x, v1.y, v1.z, v1.w};
#pragma unroll
    for (int j = 0; j < 8; ++j) {
        const unsigned short h = f2bf_rne(f[j]);
        hi[j] = (short)h;
        lo[j] = (short)f2bf_rne(f[j] - bf2f(h));
    }
}

__global__ __launch_bounds__(256) void out_mfma(const float* __restrict__ x,
                                                const unsigned short* __restrict__ frag,
                                                float* __restrict__ out) {
    const int tid  = threadIdx.x;
    const int lane = tid & 63;
    const int wv   = tid >> 6;
    const int blk  = blockIdx.x;          // 4096 blocks, 256 pixels each
    const int b    = blk >> 8;            // 256 blocks per batch
    const int row  = lane & 15;
    const int g    = lane >> 4;

    // Stage the batch's 16 KiB of B-fragments into LDS (1024 x 16 B).
    __shared__ unsigned short bfr[16 * 64 * 8];
    {
        const s16x8* s = (const s16x8*)(frag + (size_t)b * FRAG_USHORT_PER_B);
        s16x8* d = (s16x8*)bfr;
#pragma unroll
        for (int it = 0; it < 4; ++it) d[tid + it * 256] = s[tid + it * 256];
    }
    __syncthreads();

    const size_t pix0 = (size_t)blk * 256 + wv * 64;
    const float* xb = x + (pix0 + row) * CC + g * 8;
    float* ob = out + (pix0 + (g << 2)) * CC + row;   // row here = lane&15 = t-in-tile

    // preload rowblock 0 (kstep0: 8 floats at +0, kstep1: 8 floats at +32)
    float4 c0 = *(const float4*)(xb);
    float4 c1 = *(const float4*)(xb + 4);
    float4 c2 = *(const float4*)(xb + 32);
    float4 c3 = *(const float4*)(xb + 36);

    for (int rb = 0; rb < 4; ++rb) {
        s16x8 ah0, al0, ah1, al1;
        split8(c0, c1, ah0, al0);
        split8(c2, c3, ah1, al1);
        if (rb < 3) {                       // prefetch next 16-row block
            const float* nx = xb + (size_t)(rb + 1) * 16 * CC;
            c0 = *(const float4*)(nx);
            c1 = *(const float4*)(nx + 4);
            c2 = *(const float4*)(nx + 32);
            c3 = *(const float4*)(nx + 36);
        }
#pragma unroll
        for (int tcol = 0; tcol < 4; ++tcol) {
            const s16x8 bh0 = *(const s16x8*)&bfr[((((tcol * 2 + 0) * 2 + 0) * 64) + lane) * 8];
            const s16x8 bl0 = *(const s16x8*)&bfr[((((tcol * 2 + 0) * 2 + 1) * 64) + lane) * 8];
            const s16x8 bh1 = *(const s16x8*)&bfr[((((tcol * 2 + 1) * 2 + 0) * 64) + lane) * 8];
            const s16x8 bl1 = *(const s16x8*)&bfr[((((tcol * 2 + 1) * 2 + 1) * 64) + lane) * 8];
            f32x4 acc = {0.f, 0.f, 0.f, 0.f};
            acc = __builtin_amdgcn_mfma_f32_16x16x32_bf16(ah0, bh0, acc, 0, 0, 0);
            acc = __builtin_amdgcn_mfma_f32_16x16x32_bf16(ah1, bh1, acc, 0, 0, 0);
            acc = __builtin_amdgcn_mfma_f32_16x16x32_bf16(al0, bh0, acc, 0, 0, 0);
            acc = __builtin_amdgcn_mfma_f32_16x16x32_bf16(al1, bh1, acc, 0, 0, 0);
            acc = __builtin_amdgcn_mfma_f32_16x16x32_bf16(ah0, bl0, acc, 0, 0, 0);
            acc = __builtin_amdgcn_mfma_f32_16x16x32_bf16(ah1, bl1, acc, 0, 0, 0);

            float* o = ob + (size_t)rb * 16 * CC + tcol * 16;
#pragma unroll
            for (int r = 0; r < 4; ++r)
                o[(size_t)r * CC] = gelu_exact(acc[r]);
        }
    }
}

// ---------------------------------------------------------------------------
extern "C" void kernel_launch(void* const* d_in, const int* in_sizes, int n_in,
                              void* d_out, int out_size, void* d_ws, size_t ws_size,
                              hipStream_t stream) {
    const float* x     = (const float*)d_in[0];   // (16,256,256,64) fp32
    const float* w_qkv = (const float*)d_in[1];   // (32,16) fp32
    float* out   = (float*)d_out;                 // (16,256,256,64) fp32
    float* part  = (float*)d_ws;                  // 1 MiB
    unsigned short* frag = (unsigned short*)(part + PART_FLOATS); // 256 KiB

    pool_partial<<<BB * NTOK * 16, 256, 0, stream>>>(x, part);
    attn_kernel<<<BB, 256, 0, stream>>>(part, w_qkv, frag);
    out_mfma<<<BB * 256, 256, 0, stream>>>(x, frag, out);
}